// Round 1
// baseline (1818.864 us; speedup 1.0000x reference)
//
#include <hip/hip_runtime.h>

// Problem constants (R=4096, S=128, V=3, F=35)
#define NPTS      524288            // R*S
#define OUT2_BASE 4718592           // NPTS*9  (rgb_in elements)

// ws layout (floats), all transposed to k-major so inner j is contiguous:
//   wT1 [105][64] @ 0      (bw1 (64,105))
//   wT2 [ 64][32] @ 6720   (bw2 (32,64))
//   vT1 [ 32][32] @ 8768   (vw1 (32,32))
//   vT2 [ 32][32] @ 9792   (vw2 (32,32))
//   rT1 [ 96][32] @ 10816  (rw1 (32,96))
//   rT2 [ 32][16] @ 13888  (rw2 (16,32))
// total 14400 floats = 57.6 KB in d_ws (re-written every launch; ws is re-poisoned)

__device__ __forceinline__ float eluf(float x) { return x > 0.f ? x : __expf(x) - 1.f; }
__device__ __forceinline__ float sigm(float x) { return 1.f / (1.f + __expf(-x)); }

__global__ void transpose_weights_k(const float* __restrict__ bw1, const float* __restrict__ bw2,
                                    const float* __restrict__ vw1, const float* __restrict__ vw2,
                                    const float* __restrict__ rw1, const float* __restrict__ rw2,
                                    float* __restrict__ ws)
{
    int i = blockIdx.x * blockDim.x + threadIdx.x;
    if (i < 6720) {
        int k = i >> 6, j = i & 63;
        ws[i] = bw1[j * 105 + k];
    } else if (i < 8768) {
        int t = i - 6720, k = t >> 5, j = t & 31;
        ws[i] = bw2[j * 64 + k];
    } else if (i < 9792) {
        int t = i - 8768, k = t >> 5, j = t & 31;
        ws[i] = vw1[j * 32 + k];
    } else if (i < 10816) {
        int t = i - 9792, k = t >> 5, j = t & 31;
        ws[i] = vw2[j * 32 + k];
    } else if (i < 13888) {
        int t = i - 10816, k = t >> 5, j = t & 31;
        ws[i] = rw1[j * 96 + k];
    } else if (i < 14400) {
        int t = i - 13888, k = t >> 4, j = t & 15;
        ws[i] = rw2[j * 32 + k];
    }
}

__global__ __launch_bounds__(256) void nerf_head_k(
    const float* __restrict__ feat, const float* __restrict__ ws,
    const float* __restrict__ bb1, const float* __restrict__ bb2,
    const float* __restrict__ vb1, const float* __restrict__ vb2,
    const float* __restrict__ rb1, const float* __restrict__ rb2,
    const float* __restrict__ rw3, const float* __restrict__ rb3,
    float* __restrict__ out)
{
    int p = blockIdx.x * blockDim.x + threadIdx.x;
    if (p >= NPTS) return;
    const float* fp = feat + (long long)p * 105;
    const float* wT1 = ws;
    const float* wT2 = ws + 6720;
    const float* vT1 = ws + 8768;
    const float* vT2 = ws + 9792;
    const float* rT1 = ws + 10816;
    const float* rT2 = ws + 13888;

    // g1 = bb1 + W1[:, 0:35]·mean + W1[:, 35:70]·var   (view-invariant part of layer 1)
    float g1[64];
#pragma unroll
    for (int j = 0; j < 64; ++j) g1[j] = bb1[j];
#pragma unroll 2
    for (int k = 0; k < 35; ++k) {
        float a = fp[k], b = fp[35 + k], c = fp[70 + k];
        float m = (a + b + c) * (1.f / 3.f);
        float da = a - m, db = b - m, dc = c - m;
        float vv = (da * da + db * db + dc * dc) * (1.f / 3.f);
        const float* w1 = wT1 + k * 64;
        const float* w2 = wT1 + (35 + k) * 64;
#pragma unroll
        for (int j = 0; j < 64; ++j) g1[j] += m * w1[j] + vv * w2[j];
    }

    // r1 accumulates rw1 @ h directly (h = concat over views of final 32-d features)
    float r1[32];
#pragma unroll
    for (int j = 0; j < 32; ++j) r1[j] = rb1[j];

#pragma unroll 1
    for (int v = 0; v < 3; ++v) {
        const float* fv = fp + v * 35;

        // layer 1 (view part) : h1 = elu(g1 + W1[:, 70:105]·feat_v)
        float h1[64];
#pragma unroll
        for (int j = 0; j < 64; ++j) h1[j] = g1[j];
#pragma unroll 2
        for (int k = 0; k < 35; ++k) {
            float x = fv[k];
            const float* w = wT1 + (70 + k) * 64;
#pragma unroll
            for (int j = 0; j < 64; ++j) h1[j] += x * w[j];
        }
#pragma unroll
        for (int j = 0; j < 64; ++j) h1[j] = eluf(h1[j]);

        // layer 2 : h2 = elu(bw2 @ h1 + bb2)
        float h2[32];
#pragma unroll
        for (int j = 0; j < 32; ++j) h2[j] = bb2[j];
#pragma unroll 2
        for (int k = 0; k < 64; ++k) {
            float x = h1[k];
            const float* w = wT2 + k * 32;
#pragma unroll
            for (int j = 0; j < 32; ++j) h2[j] += x * w[j];
        }
#pragma unroll
        for (int j = 0; j < 32; ++j) h2[j] = eluf(h2[j]);

        // vis branch : t2 = elu(vw2 @ elu(vw1 @ (h2/3) + vb1) + vb2)
        float t1[32];
#pragma unroll
        for (int j = 0; j < 32; ++j) t1[j] = vb1[j];
#pragma unroll 2
        for (int k = 0; k < 32; ++k) {
            float x = h2[k] * (1.f / 3.f);
            const float* w = vT1 + k * 32;
#pragma unroll
            for (int j = 0; j < 32; ++j) t1[j] += x * w[j];
        }
#pragma unroll
        for (int j = 0; j < 32; ++j) t1[j] = eluf(t1[j]);

        float t2[32];
#pragma unroll
        for (int j = 0; j < 32; ++j) t2[j] = vb2[j];
#pragma unroll 2
        for (int k = 0; k < 32; ++k) {
            float x = t1[k];
            const float* w = vT2 + k * 32;
#pragma unroll
            for (int j = 0; j < 32; ++j) t2[j] += x * w[j];
        }
#pragma unroll
        for (int j = 0; j < 32; ++j) t2[j] = eluf(t2[j]);

        // residual + fold into r1 via rw1 columns for this view
#pragma unroll 2
        for (int c = 0; c < 32; ++c) {
            float x = h2[c] + t2[c];
            const float* w = rT1 + (v * 32 + c) * 32;
#pragma unroll
            for (int j = 0; j < 32; ++j) r1[j] += x * w[j];
        }

        // rgb_in output: rgb_feat[..., :3]
        float* o1 = out + (long long)p * 9 + v * 3;
        o1[0] = fv[0]; o1[1] = fv[1]; o1[2] = fv[2];
    }

#pragma unroll
    for (int j = 0; j < 32; ++j) r1[j] = eluf(r1[j]);

    float r2[16];
#pragma unroll
    for (int j = 0; j < 16; ++j) r2[j] = rb2[j];
#pragma unroll 2
    for (int k = 0; k < 32; ++k) {
        float x = r1[k];
        const float* w = rT2 + k * 16;
#pragma unroll
        for (int j = 0; j < 16; ++j) r2[j] += x * w[j];
    }
#pragma unroll
    for (int j = 0; j < 16; ++j) r2[j] = eluf(r2[j]);

    // final 16 -> 3 + sigmoid (rw3 used untransposed; rows are contiguous)
    float* o2 = out + OUT2_BASE + (long long)p * 3;
#pragma unroll
    for (int c = 0; c < 3; ++c) {
        float s = rb3[c];
#pragma unroll
        for (int k = 0; k < 16; ++k) s += rw3[c * 16 + k] * r2[k];
        o2[c] = sigm(s);
    }
}

extern "C" void kernel_launch(void* const* d_in, const int* in_sizes, int n_in,
                              void* d_out, int out_size, void* d_ws, size_t ws_size,
                              hipStream_t stream) {
    const float* feat = (const float*)d_in[0];
    const float* bw1  = (const float*)d_in[1];
    const float* bb1  = (const float*)d_in[2];
    const float* bw2  = (const float*)d_in[3];
    const float* bb2  = (const float*)d_in[4];
    const float* vw1  = (const float*)d_in[5];
    const float* vb1  = (const float*)d_in[6];
    const float* vw2  = (const float*)d_in[7];
    const float* vb2  = (const float*)d_in[8];
    const float* rw1  = (const float*)d_in[9];
    const float* rb1  = (const float*)d_in[10];
    const float* rw2  = (const float*)d_in[11];
    const float* rb2  = (const float*)d_in[12];
    const float* rw3  = (const float*)d_in[13];
    const float* rb3  = (const float*)d_in[14];
    float* ws  = (float*)d_ws;
    float* out = (float*)d_out;

    hipLaunchKernelGGL(transpose_weights_k, dim3(57), dim3(256), 0, stream,
                       bw1, bw2, vw1, vw2, rw1, rw2, ws);
    hipLaunchKernelGGL(nerf_head_k, dim3(NPTS / 256), dim3(256), 0, stream,
                       feat, ws, bb1, bb2, vb1, vb2, rb1, rb2, rw3, rb3, out);
}

// Round 2
// 1361.972 us; speedup vs baseline: 1.3355x; 1.3355x over previous
//
#include <hip/hip_runtime.h>

// Problem constants (R=4096, S=128, V=3, F=35)
#define NPTS      524288            // R*S
#define OUT2_BASE 4718592           // NPTS*9  (rgb_in elements)
#define PPB       64                // points per block (= block threads, 1 wave)

// ws layout (floats), transposed to k-major so inner j is contiguous:
//   wT1 [105][64] @ 0      (bw1 (64,105))
//   wT2 [ 64][32] @ 6720   (bw2 (32,64))
//   vT1 [ 32][32] @ 8768   (vw1 (32,32))
//   vT2 [ 32][32] @ 9792   (vw2 (32,32))
//   rT1 [ 96][32] @ 10816  (rw1 (32,96))
//   rT2 [ 32][16] @ 13888  (rw2 (16,32))

__device__ __forceinline__ float eluf(float x) { return x > 0.f ? x : __expf(x) - 1.f; }
__device__ __forceinline__ float sigm(float x) { return 1.f / (1.f + __expf(-x)); }

__global__ void transpose_weights_k(const float* __restrict__ bw1, const float* __restrict__ bw2,
                                    const float* __restrict__ vw1, const float* __restrict__ vw2,
                                    const float* __restrict__ rw1, const float* __restrict__ rw2,
                                    float* __restrict__ ws)
{
    int i = blockIdx.x * blockDim.x + threadIdx.x;
    if (i < 6720) {
        int k = i >> 6, j = i & 63;
        ws[i] = bw1[j * 105 + k];
    } else if (i < 8768) {
        int t = i - 6720, k = t >> 5, j = t & 31;
        ws[i] = bw2[j * 64 + k];
    } else if (i < 9792) {
        int t = i - 8768, k = t >> 5, j = t & 31;
        ws[i] = vw1[j * 32 + k];
    } else if (i < 10816) {
        int t = i - 9792, k = t >> 5, j = t & 31;
        ws[i] = vw2[j * 32 + k];
    } else if (i < 13888) {
        int t = i - 10816, k = t >> 5, j = t & 31;
        ws[i] = rw1[j * 96 + k];
    } else if (i < 14400) {
        int t = i - 13888, k = t >> 4, j = t & 15;
        ws[i] = rw2[j * 32 + k];
    }
}

__global__ __launch_bounds__(PPB) void nerf_head_k(
    const float* __restrict__ feat, const float* __restrict__ ws,
    const float* __restrict__ bb1, const float* __restrict__ bb2,
    const float* __restrict__ vb1, const float* __restrict__ vb2,
    const float* __restrict__ rb1, const float* __restrict__ rb2,
    const float* __restrict__ rw3, const float* __restrict__ rb3,
    float* __restrict__ out)
{
    // 64 pts * 105 floats = 26.88 KB feat stage + 768 B out stage = 27.6 KB LDS
    // -> 5 blocks/CU (LDS-limited). Stride-105 LDS reads: 105 % 32 = 9,
    // coprime with 32 -> 2 lanes/bank for wave64 = conflict-free.
    __shared__ float sfeat[PPB * 105];
    __shared__ float souts[PPB * 3];

    const int tid = threadIdx.x;
    const long long pbase = (long long)blockIdx.x * PPB;   // first point of tile

    // ---- coalesced global->LDS staging (float4: 1680 vec4 per tile) ----
    const float4* f4 = (const float4*)(feat + pbase * 105);
    float4* s4 = (float4*)sfeat;
#pragma unroll 4
    for (int i = tid; i < (PPB * 105) / 4; i += PPB) s4[i] = f4[i];
    __syncthreads();

    // ---- rgb_in output (coalesced copy from LDS): out[p*9 + v*3 + c] ----
    {
        float* o1 = out + pbase * 9;
#pragma unroll
        for (int i = tid; i < PPB * 9; i += PPB) {
            int pl = i / 9, r = i - pl * 9;
            int v = r / 3, c = r - v * 3;
            o1[i] = sfeat[pl * 105 + v * 35 + c];
        }
    }

    const float* fp  = sfeat + tid * 105;
    const float* wT1 = ws;
    const float* wT2 = ws + 6720;
    const float* vT1 = ws + 8768;
    const float* vT2 = ws + 9792;
    const float* rT1 = ws + 10816;
    const float* rT2 = ws + 13888;

    // g1 = bb1 + W1[:, 0:35]·mean + W1[:, 35:70]·var   (view-invariant part)
    float g1[64];
#pragma unroll
    for (int j = 0; j < 64; ++j) g1[j] = bb1[j];
#pragma unroll 2
    for (int k = 0; k < 35; ++k) {
        float a = fp[k], b = fp[35 + k], c = fp[70 + k];
        float m = (a + b + c) * (1.f / 3.f);
        float da = a - m, db = b - m, dc = c - m;
        float vv = (da * da + db * db + dc * dc) * (1.f / 3.f);
        const float* w1 = wT1 + k * 64;
        const float* w2 = wT1 + (35 + k) * 64;
#pragma unroll
        for (int j = 0; j < 64; ++j) g1[j] += m * w1[j] + vv * w2[j];
    }

    // r1 accumulates rw1 @ h directly (h = concat over views of final 32-d feats)
    float r1[32];
#pragma unroll
    for (int j = 0; j < 32; ++j) r1[j] = rb1[j];

#pragma unroll 1
    for (int v = 0; v < 3; ++v) {
        const float* fv = fp + v * 35;

        // layer 1 (view part): h1 = elu(g1 + W1[:, 70:105]·feat_v)
        float h1[64];
#pragma unroll
        for (int j = 0; j < 64; ++j) h1[j] = g1[j];
#pragma unroll 2
        for (int k = 0; k < 35; ++k) {
            float x = fv[k];
            const float* w = wT1 + (70 + k) * 64;
#pragma unroll
            for (int j = 0; j < 64; ++j) h1[j] += x * w[j];
        }
#pragma unroll
        for (int j = 0; j < 64; ++j) h1[j] = eluf(h1[j]);

        // layer 2: h2 = elu(bw2 @ h1 + bb2)
        float h2[32];
#pragma unroll
        for (int j = 0; j < 32; ++j) h2[j] = bb2[j];
#pragma unroll 2
        for (int k = 0; k < 64; ++k) {
            float x = h1[k];
            const float* w = wT2 + k * 32;
#pragma unroll
            for (int j = 0; j < 32; ++j) h2[j] += x * w[j];
        }
#pragma unroll
        for (int j = 0; j < 32; ++j) h2[j] = eluf(h2[j]);

        // vis branch: t2 = elu(vw2 @ elu(vw1 @ (h2/3) + vb1) + vb2)
        float t1[32];
#pragma unroll
        for (int j = 0; j < 32; ++j) t1[j] = vb1[j];
#pragma unroll 2
        for (int k = 0; k < 32; ++k) {
            float x = h2[k] * (1.f / 3.f);
            const float* w = vT1 + k * 32;
#pragma unroll
            for (int j = 0; j < 32; ++j) t1[j] += x * w[j];
        }
#pragma unroll
        for (int j = 0; j < 32; ++j) t1[j] = eluf(t1[j]);

        float t2[32];
#pragma unroll
        for (int j = 0; j < 32; ++j) t2[j] = vb2[j];
#pragma unroll 2
        for (int k = 0; k < 32; ++k) {
            float x = t1[k];
            const float* w = vT2 + k * 32;
#pragma unroll
            for (int j = 0; j < 32; ++j) t2[j] += x * w[j];
        }
#pragma unroll
        for (int j = 0; j < 32; ++j) t2[j] = eluf(t2[j]);

        // residual + fold into r1 via rw1 columns for this view
#pragma unroll 2
        for (int c = 0; c < 32; ++c) {
            float x = h2[c] + t2[c];
            const float* w = rT1 + (v * 32 + c) * 32;
#pragma unroll
            for (int j = 0; j < 32; ++j) r1[j] += x * w[j];
        }
    }

#pragma unroll
    for (int j = 0; j < 32; ++j) r1[j] = eluf(r1[j]);

    float r2[16];
#pragma unroll
    for (int j = 0; j < 16; ++j) r2[j] = rb2[j];
#pragma unroll 2
    for (int k = 0; k < 32; ++k) {
        float x = r1[k];
        const float* w = rT2 + k * 16;
#pragma unroll
        for (int j = 0; j < 16; ++j) r2[j] += x * w[j];
    }
#pragma unroll
    for (int j = 0; j < 16; ++j) r2[j] = eluf(r2[j]);

    // final 16 -> 3 + sigmoid, staged to LDS for coalesced store
#pragma unroll
    for (int c = 0; c < 3; ++c) {
        float s = rb3[c];
#pragma unroll
        for (int k = 0; k < 16; ++k) s += rw3[c * 16 + k] * r2[k];
        souts[tid * 3 + c] = sigm(s);
    }
    __syncthreads();
    {
        float* o2 = out + OUT2_BASE + pbase * 3;
#pragma unroll
        for (int i = tid; i < PPB * 3; i += PPB) o2[i] = souts[i];
    }
}

extern "C" void kernel_launch(void* const* d_in, const int* in_sizes, int n_in,
                              void* d_out, int out_size, void* d_ws, size_t ws_size,
                              hipStream_t stream) {
    const float* feat = (const float*)d_in[0];
    const float* bw1  = (const float*)d_in[1];
    const float* bb1  = (const float*)d_in[2];
    const float* bw2  = (const float*)d_in[3];
    const float* bb2  = (const float*)d_in[4];
    const float* vw1  = (const float*)d_in[5];
    const float* vb1  = (const float*)d_in[6];
    const float* vw2  = (const float*)d_in[7];
    const float* vb2  = (const float*)d_in[8];
    const float* rw1  = (const float*)d_in[9];
    const float* rb1  = (const float*)d_in[10];
    const float* rw2  = (const float*)d_in[11];
    const float* rb2  = (const float*)d_in[12];
    const float* rw3  = (const float*)d_in[13];
    const float* rb3  = (const float*)d_in[14];
    float* ws  = (float*)d_ws;
    float* out = (float*)d_out;

    hipLaunchKernelGGL(transpose_weights_k, dim3(57), dim3(256), 0, stream,
                       bw1, bw2, vw1, vw2, rw1, rw2, ws);
    hipLaunchKernelGGL(nerf_head_k, dim3(NPTS / PPB), dim3(PPB), 0, stream,
                       feat, ws, bb1, bb2, vb1, vb2, rb1, rb2, rw3, rb3, out);
}

// Round 3
// 562.170 us; speedup vs baseline: 3.2354x; 2.4227x over previous
//
#include <hip/hip_runtime.h>

// Problem constants (R=4096, S=128, V=3, F=35)
#define NPTS      524288            // R*S
#define OUT2_BASE 4718592           // NPTS*9  (rgb_in elements)

// ---- MFMA types (gfx950, 16x16x32 bf16) ----
using bf16x8 = __attribute__((ext_vector_type(8))) short;   // A/B frag: 8 bf16
using f32x4  = __attribute__((ext_vector_type(4))) float;   // C/D frag

// Weight workspace layout (ushort/bf16 elements in d_ws), [N][K] row-major,
// K padded so every 8-elem chunk (16 B) is aligned; pads are ZEROED by prep.
//   WG [64][96]  @ 0      = bw1[:, 0:70] (mean+var part), cols 70..95 = 0
//   WF [64][72]  @ 6144   = bw1[:, 70:105] (view part),  cols 35..71 = 0
//   W2 [32][72]  @ 10752  = bw2, cols 64..71 = 0
//   V1 [32][40]  @ 13056  = vw1 / 3  (x/num_views folded), cols 32..39 = 0
//   V2 [32][40]  @ 14336  = vw2, cols 32..39 = 0
//   R1 [32][104] @ 15616  = rw1, cols 96..103 = 0
//   R2 [16][40]  @ 18944  = rw2, cols 32..39 = 0
// total 19584 ushort = 39168 B

__device__ __forceinline__ ushort f2bf(float f) {
    union { float f; unsigned u; } v; v.f = f;
    unsigned u = v.u;
    unsigned r = u + 0x7fffu + ((u >> 16) & 1u);   // RTNE
    return (ushort)(r >> 16);
}
__device__ __forceinline__ float eluf(float x) {
    // x>0: x + e^0 - 1 = x ; x<=0: 0 + e^x - 1
    return fmaxf(x, 0.f) + __expf(fminf(x, 0.f)) - 1.f;
}
__device__ __forceinline__ float sigm(float x) { return 1.f / (1.f + __expf(-x)); }

__global__ void prep_k(const float* __restrict__ bw1, const float* __restrict__ bw2,
                       const float* __restrict__ vw1, const float* __restrict__ vw2,
                       const float* __restrict__ rw1, const float* __restrict__ rw2,
                       ushort* __restrict__ w)
{
    int i = blockIdx.x * 256 + threadIdx.x;
    if (i < 6144) {                                   // WG [64][96]
        int n = i / 96, k = i % 96;
        w[i] = f2bf(k < 70 ? bw1[n * 105 + k] : 0.f);
    } else if (i < 10752) {                           // WF [64][72]
        int t = i - 6144, n = t / 72, k = t % 72;
        w[i] = f2bf(k < 35 ? bw1[n * 105 + 70 + k] : 0.f);
    } else if (i < 13056) {                           // W2 [32][72]
        int t = i - 10752, n = t / 72, k = t % 72;
        w[i] = f2bf(k < 64 ? bw2[n * 64 + k] : 0.f);
    } else if (i < 14336) {                           // V1 [32][40] (/3)
        int t = i - 13056, n = t / 40, k = t % 40;
        w[i] = f2bf(k < 32 ? vw1[n * 32 + k] * (1.f / 3.f) : 0.f);
    } else if (i < 15616) {                           // V2 [32][40]
        int t = i - 14336, n = t / 40, k = t % 40;
        w[i] = f2bf(k < 32 ? vw2[n * 32 + k] : 0.f);
    } else if (i < 18944) {                           // R1 [32][104]
        int t = i - 15616, n = t / 104, k = t % 104;
        w[i] = f2bf(k < 96 ? rw1[n * 96 + k] : 0.f);
    } else if (i < 19584) {                           // R2 [16][40]
        int t = i - 18944, n = t / 40, k = t % 40;
        w[i] = f2bf(k < 32 ? rw2[n * 32 + k] : 0.f);
    }
}

// One wave per block, 16 points per block. Rows of view-GEMMs: row = v*16 + p
// so C-frag lanes (row = quad*4+reg) align between the per-point GEMM (rows=p)
// and per-view GEMMs (rows=v*16+p): in-register broadcast add, no shuffles.
__global__ __launch_bounds__(64) void mlp_k(
    const float* __restrict__ feat, const ushort* __restrict__ w,
    const float* __restrict__ bb1, const float* __restrict__ bb2,
    const float* __restrict__ vb1, const float* __restrict__ vb2,
    const float* __restrict__ rb1, const float* __restrict__ rb2,
    const float* __restrict__ rw3, const float* __restrict__ rb3,
    float* __restrict__ out)
{
    __shared__ __align__(16) float  sfeat[16 * 105];   // 6720 B
    __shared__ __align__(16) ushort bufA[48 * 72];     // 6912 B (Xg aliases [16][96])
    __shared__ __align__(16) ushort bufB[48 * 72];     // 6912 B (Xf lives here [48][72])

    const int lane = threadIdx.x;
    const int n16  = lane & 15;
    const int quad = lane >> 4;
    const long long pbase = (long long)blockIdx.x * 16;

    const ushort* WG = w;
    const ushort* WF = w + 6144;
    const ushort* W2 = w + 10752;
    const ushort* V1 = w + 13056;
    const ushort* V2 = w + 14336;
    const ushort* R1 = w + 15616;
    const ushort* R2 = w + 18944;

    // per-lane biases (column = nt*16 + n16)
    float bb1v[4], bb2v[2], vb1v[2], vb2v[2], rb1v[2], rb2v;
#pragma unroll
    for (int nt = 0; nt < 4; ++nt) bb1v[nt] = bb1[nt * 16 + n16];
#pragma unroll
    for (int nt = 0; nt < 2; ++nt) {
        bb2v[nt] = bb2[nt * 16 + n16];
        vb1v[nt] = vb1[nt * 16 + n16];
        vb2v[nt] = vb2[nt * 16 + n16];
        rb1v[nt] = rb1[nt * 16 + n16];
    }
    rb2v = rb2[n16];

    // ---- stage 16 points (coalesced float4) ----
    {
        const float4* f4 = (const float4*)(feat + pbase * 105);
        float4* s4 = (float4*)sfeat;
#pragma unroll
        for (int i = 0; i < 7; ++i) {
            int idx = lane + i * 64;
            if (idx < 420) s4[idx] = f4[idx];
        }
    }
    __syncthreads();

    // ---- rgb_in copy (coalesced, fp32-exact) ----
    {
        float* o1 = out + pbase * 9;
#pragma unroll
        for (int i = lane; i < 144; i += 64) {
            int pl = i / 9, r = i - pl * 9;
            int v = r / 3, c = r - v * 3;
            o1[i] = sfeat[pl * 105 + v * 35 + c];
        }
    }

    // ---- build Xf [48][72] (bufB) and Xg [16][96] (bufA) ----
    ushort* Xg = bufA;
    ushort* Xf = bufB;
#pragma unroll
    for (int i = 0; i < 16; ++i) {
        int idx = i * 64 + lane;          // 0..1023
        int p = idx >> 6, k = idx & 63;
        if (k < 35) {
            float a = sfeat[p * 105 + k];
            float b = sfeat[p * 105 + 35 + k];
            float c = sfeat[p * 105 + 70 + k];
            float m  = (a + b + c) * (1.f / 3.f);
            float da = a - m, db = b - m, dc = c - m;
            float vv = (da * da + db * db + dc * dc) * (1.f / 3.f);
            Xf[(0 * 16 + p) * 72 + k] = f2bf(a);
            Xf[(1 * 16 + p) * 72 + k] = f2bf(b);
            Xf[(2 * 16 + p) * 72 + k] = f2bf(c);
            Xg[p * 96 + k]      = f2bf(m);
            Xg[p * 96 + 35 + k] = f2bf(vv);
        } else {
            Xf[(0 * 16 + p) * 72 + k] = 0;
            Xf[(1 * 16 + p) * 72 + k] = 0;
            Xf[(2 * 16 + p) * 72 + k] = 0;
            if (k < 61) Xg[p * 96 + 35 + k] = 0;   // cols 70..95
        }
    }
    __syncthreads();

    const f32x4 Z = {0.f, 0.f, 0.f, 0.f};

    // ---- layer 1 ----
    f32x4 Cg[4]   = {Z, Z, Z, Z};
    f32x4 Cf[3][4] = {{Z,Z,Z,Z},{Z,Z,Z,Z},{Z,Z,Z,Z}};
#pragma unroll
    for (int ks = 0; ks < 3; ++ks) {                 // G: K=96 (mean|var)
        bf16x8 a = *(const bf16x8*)(Xg + n16 * 96 + ks * 32 + quad * 8);
#pragma unroll
        for (int nt = 0; nt < 4; ++nt) {
            bf16x8 b = *(const bf16x8*)(WG + (nt * 16 + n16) * 96 + ks * 32 + quad * 8);
            Cg[nt] = __builtin_amdgcn_mfma_f32_16x16x32_bf16(a, b, Cg[nt], 0, 0, 0);
        }
    }
#pragma unroll
    for (int ks = 0; ks < 2; ++ks) {                 // F: K=64 (view feat)
        bf16x8 a0 = *(const bf16x8*)(Xf + (0 * 16 + n16) * 72 + ks * 32 + quad * 8);
        bf16x8 a1 = *(const bf16x8*)(Xf + (1 * 16 + n16) * 72 + ks * 32 + quad * 8);
        bf16x8 a2 = *(const bf16x8*)(Xf + (2 * 16 + n16) * 72 + ks * 32 + quad * 8);
#pragma unroll
        for (int nt = 0; nt < 4; ++nt) {
            bf16x8 b = *(const bf16x8*)(WF + (nt * 16 + n16) * 72 + ks * 32 + quad * 8);
            Cf[0][nt] = __builtin_amdgcn_mfma_f32_16x16x32_bf16(a0, b, Cf[0][nt], 0, 0, 0);
            Cf[1][nt] = __builtin_amdgcn_mfma_f32_16x16x32_bf16(a1, b, Cf[1][nt], 0, 0, 0);
            Cf[2][nt] = __builtin_amdgcn_mfma_f32_16x16x32_bf16(a2, b, Cf[2][nt], 0, 0, 0);
        }
    }
    __syncthreads();
    // h1 = elu(Cf + Cg + bb1) -> bufA [48][72]
#pragma unroll
    for (int mt = 0; mt < 3; ++mt)
#pragma unroll
        for (int nt = 0; nt < 4; ++nt)
#pragma unroll
            for (int r = 0; r < 4; ++r) {
                float x = Cf[mt][nt][r] + Cg[nt][r] + bb1v[nt];
                int row = mt * 16 + quad * 4 + r;
                bufA[row * 72 + nt * 16 + n16] = f2bf(eluf(x));
            }
    __syncthreads();

    // ---- layer 2: h2 = elu(h1 @ W2^T + bb2), keep fp32 in regs too ----
    f32x4 C2[3][2] = {{Z,Z},{Z,Z},{Z,Z}};
#pragma unroll
    for (int ks = 0; ks < 2; ++ks) {
        bf16x8 a0 = *(const bf16x8*)(bufA + (0 * 16 + n16) * 72 + ks * 32 + quad * 8);
        bf16x8 a1 = *(const bf16x8*)(bufA + (1 * 16 + n16) * 72 + ks * 32 + quad * 8);
        bf16x8 a2 = *(const bf16x8*)(bufA + (2 * 16 + n16) * 72 + ks * 32 + quad * 8);
#pragma unroll
        for (int nt = 0; nt < 2; ++nt) {
            bf16x8 b = *(const bf16x8*)(W2 + (nt * 16 + n16) * 72 + ks * 32 + quad * 8);
            C2[0][nt] = __builtin_amdgcn_mfma_f32_16x16x32_bf16(a0, b, C2[0][nt], 0, 0, 0);
            C2[1][nt] = __builtin_amdgcn_mfma_f32_16x16x32_bf16(a1, b, C2[1][nt], 0, 0, 0);
            C2[2][nt] = __builtin_amdgcn_mfma_f32_16x16x32_bf16(a2, b, C2[2][nt], 0, 0, 0);
        }
    }
    __syncthreads();
    float h2r[3][2][4];
#pragma unroll
    for (int mt = 0; mt < 3; ++mt)
#pragma unroll
        for (int nt = 0; nt < 2; ++nt)
#pragma unroll
            for (int r = 0; r < 4; ++r) {
                float x = eluf(C2[mt][nt][r] + bb2v[nt]);
                h2r[mt][nt][r] = x;
                int row = mt * 16 + quad * 4 + r;
                bufB[row * 72 + nt * 16 + n16] = f2bf(x);
            }
    __syncthreads();

    // ---- vis layer 1: t1 = elu(h2 @ (V1/3)^T + vb1) ----
    f32x4 T1[3][2] = {{Z,Z},{Z,Z},{Z,Z}};
    {
        bf16x8 a0 = *(const bf16x8*)(bufB + (0 * 16 + n16) * 72 + quad * 8);
        bf16x8 a1 = *(const bf16x8*)(bufB + (1 * 16 + n16) * 72 + quad * 8);
        bf16x8 a2 = *(const bf16x8*)(bufB + (2 * 16 + n16) * 72 + quad * 8);
#pragma unroll
        for (int nt = 0; nt < 2; ++nt) {
            bf16x8 b = *(const bf16x8*)(V1 + (nt * 16 + n16) * 40 + quad * 8);
            T1[0][nt] = __builtin_amdgcn_mfma_f32_16x16x32_bf16(a0, b, T1[0][nt], 0, 0, 0);
            T1[1][nt] = __builtin_amdgcn_mfma_f32_16x16x32_bf16(a1, b, T1[1][nt], 0, 0, 0);
            T1[2][nt] = __builtin_amdgcn_mfma_f32_16x16x32_bf16(a2, b, T1[2][nt], 0, 0, 0);
        }
    }
    __syncthreads();
#pragma unroll
    for (int mt = 0; mt < 3; ++mt)
#pragma unroll
        for (int nt = 0; nt < 2; ++nt)
#pragma unroll
            for (int r = 0; r < 4; ++r) {
                int row = mt * 16 + quad * 4 + r;
                bufA[row * 72 + nt * 16 + n16] = f2bf(eluf(T1[mt][nt][r] + vb1v[nt]));
            }
    __syncthreads();

    // ---- vis layer 2 + residual: x = h2 + elu(t1 @ V2^T + vb2) -> bufB [16][104] ----
    f32x4 T2[3][2] = {{Z,Z},{Z,Z},{Z,Z}};
    {
        bf16x8 a0 = *(const bf16x8*)(bufA + (0 * 16 + n16) * 72 + quad * 8);
        bf16x8 a1 = *(const bf16x8*)(bufA + (1 * 16 + n16) * 72 + quad * 8);
        bf16x8 a2 = *(const bf16x8*)(bufA + (2 * 16 + n16) * 72 + quad * 8);
#pragma unroll
        for (int nt = 0; nt < 2; ++nt) {
            bf16x8 b = *(const bf16x8*)(V2 + (nt * 16 + n16) * 40 + quad * 8);
            T2[0][nt] = __builtin_amdgcn_mfma_f32_16x16x32_bf16(a0, b, T2[0][nt], 0, 0, 0);
            T2[1][nt] = __builtin_amdgcn_mfma_f32_16x16x32_bf16(a1, b, T2[1][nt], 0, 0, 0);
            T2[2][nt] = __builtin_amdgcn_mfma_f32_16x16x32_bf16(a2, b, T2[2][nt], 0, 0, 0);
        }
    }
    __syncthreads();
#pragma unroll
    for (int mt = 0; mt < 3; ++mt)
#pragma unroll
        for (int nt = 0; nt < 2; ++nt)
#pragma unroll
            for (int r = 0; r < 4; ++r) {
                float x = h2r[mt][nt][r] + eluf(T2[mt][nt][r] + vb2v[nt]);
                int p   = quad * 4 + r;
                int col = mt * 32 + nt * 16 + n16;     // v*32 + c : concat layout
                bufB[p * 104 + col] = f2bf(x);
            }
    __syncthreads();

    // ---- r1 = elu(x2 @ R1^T + rb1) : [16][96] x [96][32] ----
    f32x4 CR[2] = {Z, Z};
#pragma unroll
    for (int ks = 0; ks < 3; ++ks) {
        bf16x8 a = *(const bf16x8*)(bufB + n16 * 104 + ks * 32 + quad * 8);
#pragma unroll
        for (int nt = 0; nt < 2; ++nt) {
            bf16x8 b = *(const bf16x8*)(R1 + (nt * 16 + n16) * 104 + ks * 32 + quad * 8);
            CR[nt] = __builtin_amdgcn_mfma_f32_16x16x32_bf16(a, b, CR[nt], 0, 0, 0);
        }
    }
    __syncthreads();
#pragma unroll
    for (int nt = 0; nt < 2; ++nt)
#pragma unroll
        for (int r = 0; r < 4; ++r) {
            int row = quad * 4 + r;
            bufA[row * 40 + nt * 16 + n16] = f2bf(eluf(CR[nt][r] + rb1v[nt]));
        }
    __syncthreads();

    // ---- r2 = elu(r1 @ R2^T + rb2) : [16][32] x [32][16] -> fp32 [16][20] ----
    f32x4 C3 = Z;
    {
        bf16x8 a = *(const bf16x8*)(bufA + n16 * 40 + quad * 8);
        bf16x8 b = *(const bf16x8*)(R2 + n16 * 40 + quad * 8);
        C3 = __builtin_amdgcn_mfma_f32_16x16x32_bf16(a, b, C3, 0, 0, 0);
    }
    __syncthreads();
    float* r2b = (float*)bufB;
#pragma unroll
    for (int r = 0; r < 4; ++r)
        r2b[(quad * 4 + r) * 20 + n16] = eluf(C3[r] + rb2v);
    __syncthreads();

    // ---- final 16 -> 3 + sigmoid (fp32), coalesced store ----
    if (lane < 48) {
        int p = lane / 3, c = lane - (lane / 3) * 3;
        float s = rb3[c];
        const float* rr = r2b + p * 20;
        const float* w3 = rw3 + c * 16;
#pragma unroll
        for (int k2 = 0; k2 < 16; ++k2) s += rr[k2] * w3[k2];
        out[OUT2_BASE + pbase * 3 + lane] = sigm(s);
    }
}

extern "C" void kernel_launch(void* const* d_in, const int* in_sizes, int n_in,
                              void* d_out, int out_size, void* d_ws, size_t ws_size,
                              hipStream_t stream) {
    const float* feat = (const float*)d_in[0];
    const float* bw1  = (const float*)d_in[1];
    const float* bb1  = (const float*)d_in[2];
    const float* bw2  = (const float*)d_in[3];
    const float* bb2  = (const float*)d_in[4];
    const float* vw1  = (const float*)d_in[5];
    const float* vb1  = (const float*)d_in[6];
    const float* vw2  = (const float*)d_in[7];
    const float* vb2  = (const float*)d_in[8];
    const float* rw1  = (const float*)d_in[9];
    const float* rb1  = (const float*)d_in[10];
    const float* rw2  = (const float*)d_in[11];
    const float* rb2  = (const float*)d_in[12];
    const float* rw3  = (const float*)d_in[13];
    const float* rb3  = (const float*)d_in[14];
    ushort* w  = (ushort*)d_ws;
    float* out = (float*)d_out;

    hipLaunchKernelGGL(prep_k, dim3(77), dim3(256), 0, stream,
                       bw1, bw2, vw1, vw2, rw1, rw2, w);
    hipLaunchKernelGGL(mlp_k, dim3(NPTS / 16), dim3(64), 0, stream,
                       feat, w, bb1, bb2, vb1, vb2, rb1, rb2, rw3, rb3, out);
}

// Round 4
// 435.733 us; speedup vs baseline: 4.1743x; 1.2902x over previous
//
#include <hip/hip_runtime.h>
#include <hip/hip_bf16.h>

// Problem constants (R=4096, S=128, V=3, F=35)
#define NPTS      524288            // R*S
#define OUT2_BASE 4718592           // NPTS*9  (rgb_in elements)

using bf16x8 = __attribute__((ext_vector_type(8))) short;   // MFMA A/B frag
using f32x4  = __attribute__((ext_vector_type(4))) float;   // MFMA C/D frag

// Weight workspace (ushort/bf16 in d_ws), [N][K] row-major, K padded, pads ZEROED:
//   WG [64][96]  @ 0      = bw1[:, 0:70]  (mean|var part), cols 70..95 = 0
//   WF [64][72]  @ 6144   = bw1[:, 70:105](view part),     cols 35..71 = 0
//   W2 [32][72]  @ 10752  = bw2,  cols 64..71 = 0
//   V1 [32][40]  @ 13056  = vw1/3 (x/num_views folded),    cols 32..39 = 0
//   V2 [32][40]  @ 14336  = vw2,  cols 32..39 = 0
//   R1 [32][104] @ 15616  = rw1,  cols 96..103 = 0
//   R2 [16][40]  @ 18944  = rw2,  cols 32..39 = 0

__device__ __forceinline__ ushort f2bf(float f) {
    union { float f; unsigned u; } v; v.f = f;
    unsigned u = v.u;
    unsigned r = u + 0x7fffu + ((u >> 16) & 1u);   // RTNE
    return (ushort)(r >> 16);
}
__device__ __forceinline__ uint pack2(float a, float b) {   // lo=bf16(a), hi=bf16(b)
    union { __hip_bfloat162 h; uint u; } cv;
    cv.h = __float22bfloat162_rn(make_float2(a, b));
    return cv.u;
}
__device__ __forceinline__ float eluf(float x) {
    return fmaxf(x, 0.f) + __expf(fminf(x, 0.f)) - 1.f;
}
__device__ __forceinline__ float sigm(float x) { return 1.f / (1.f + __expf(-x)); }

__global__ void prep_k(const float* __restrict__ bw1, const float* __restrict__ bw2,
                       const float* __restrict__ vw1, const float* __restrict__ vw2,
                       const float* __restrict__ rw1, const float* __restrict__ rw2,
                       ushort* __restrict__ w)
{
    int i = blockIdx.x * 256 + threadIdx.x;
    if (i < 6144) {                                   // WG [64][96]
        int n = i / 96, k = i % 96;
        w[i] = f2bf(k < 70 ? bw1[n * 105 + k] : 0.f);
    } else if (i < 10752) {                           // WF [64][72]
        int t = i - 6144, n = t / 72, k = t % 72;
        w[i] = f2bf(k < 35 ? bw1[n * 105 + 70 + k] : 0.f);
    } else if (i < 13056) {                           // W2 [32][72]
        int t = i - 10752, n = t / 72, k = t % 72;
        w[i] = f2bf(k < 64 ? bw2[n * 64 + k] : 0.f);
    } else if (i < 14336) {                           // V1 [32][40] (/3 folded)
        int t = i - 13056, n = t / 40, k = t % 40;
        w[i] = f2bf(k < 32 ? vw1[n * 32 + k] * (1.f / 3.f) : 0.f);
    } else if (i < 15616) {                           // V2 [32][40]
        int t = i - 14336, n = t / 40, k = t % 40;
        w[i] = f2bf(k < 32 ? vw2[n * 32 + k] : 0.f);
    } else if (i < 18944) {                           // R1 [32][104]
        int t = i - 15616, n = t / 104, k = t % 104;
        w[i] = f2bf(k < 96 ? rw1[n * 96 + k] : 0.f);
    } else if (i < 19584) {                           // R2 [16][40]
        int t = i - 18944, n = t / 40, k = t % 40;
        w[i] = f2bf(k < 32 ? rw2[n * 32 + k] : 0.f);
    }
}

// 2 waves / block, 16 points / block. N-dim of every GEMM split across waves:
// wave w owns output cols [w*32, w*32+32) in layer1, [w*16, w*16+16) elsewhere.
// C-frag: col=lane&15, row=quad*4+r. A-frag: A[m=lane&15][k=quad*8+j].
// LDS timeline-aliased into 3 regions (17.2 KB total -> ~9 blocks/CU = 18 waves):
//   shA 6912 B: sfeat fp32[16][105] -> h1[48][72] -> t1[48][72] -> r2b fp32[16][20]
//   shB 3328 B: Xg[16][96] -> x2[16][104]
//   shC 6912 B: Xf[48][72] -> h2[48][72] -> r1[16][40]
// Pads actually read by MFMA: Xg cols 70..95, Xf cols 35..63 — need FINITE values
// (matching weight cols are zero); shB/shC are zeroed once at block start.
__global__ __launch_bounds__(128, 4) void mlp_k(
    const float* __restrict__ feat, const ushort* __restrict__ w,
    const float* __restrict__ bb1, const float* __restrict__ bb2,
    const float* __restrict__ vb1, const float* __restrict__ vb2,
    const float* __restrict__ rb1, const float* __restrict__ rb2,
    const float* __restrict__ rw3, const float* __restrict__ rb3,
    float* __restrict__ out)
{
    __shared__ __align__(16) ushort shA[3456];
    __shared__ __align__(16) ushort shB[1664];
    __shared__ __align__(16) ushort shC[3456];

    const int tid  = threadIdx.x;
    const int wv   = tid >> 6;          // wave id 0/1
    const int lane = tid & 63;
    const int n16  = lane & 15;
    const int quad = lane >> 4;
    const long long pbase = (long long)blockIdx.x * 16;

    const ushort* WG = w;
    const ushort* WF = w + 6144;
    const ushort* W2 = w + 10752;
    const ushort* V1 = w + 13056;
    const ushort* V2 = w + 14336;
    const ushort* R1 = w + 15616;
    const ushort* R2 = w + 18944;

    // per-lane biases for this wave's output columns
    float bb1v[2];
#pragma unroll
    for (int ntl = 0; ntl < 2; ++ntl) bb1v[ntl] = bb1[(wv * 2 + ntl) * 16 + n16];
    const float bb2v = bb2[wv * 16 + n16];
    const float vb1v = vb1[wv * 16 + n16];
    const float vb2v = vb2[wv * 16 + n16];
    const float rb1v = rb1[wv * 16 + n16];
    const float rb2v = rb2[n16];

    // ---- phase 1: zero shB/shC pads-to-be + stage feat fp32 into shA ----
    {
        const uint4 z = {0u, 0u, 0u, 0u};
        uint4* zb = (uint4*)shB;
        for (int i = tid; i < 208; i += 128) zb[i] = z;        // 3328 B
        uint4* zc = (uint4*)shC;
        for (int i = tid; i < 432; i += 128) zc[i] = z;        // 6912 B
        const float4* f4 = (const float4*)(feat + pbase * 105);
        float4* s4 = (float4*)shA;
        for (int i = tid; i < 420; i += 128) s4[i] = f4[i];    // 16*105 fp32
    }
    __syncthreads();

    float* sfeat = (float*)shA;

    // ---- phase 2: rgb_in copy (fp32 exact) + build Xg (shB) / Xf (shC) ----
    {
        float* o1 = out + pbase * 9;
        for (int i = tid; i < 144; i += 128) {
            int p = i / 9, r = i - p * 9, v = r / 3, c = r - v * 3;
            o1[i] = sfeat[p * 105 + v * 35 + c];
        }
        ushort* Xg = shB;
        ushort* Xf = shC;
        for (int i = tid; i < 560; i += 128) {               // 16 pts x 35 feats
            int p = i / 35, k = i - p * 35;
            float a = sfeat[p * 105 + k];
            float b = sfeat[p * 105 + 35 + k];
            float c = sfeat[p * 105 + 70 + k];
            float m  = (a + b + c) * (1.f / 3.f);
            float da = a - m, db = b - m, dc = c - m;
            float vv = (da * da + db * db + dc * dc) * (1.f / 3.f);
            uint ab = pack2(a, b);
            Xf[p * 72 + k]          = (ushort)ab;
            Xf[(16 + p) * 72 + k]   = (ushort)(ab >> 16);
            Xf[(32 + p) * 72 + k]   = f2bf(c);
            uint mv = pack2(m, vv);
            Xg[p * 96 + k]          = (ushort)mv;
            Xg[p * 96 + 35 + k]     = (ushort)(mv >> 16);
        }
    }
    __syncthreads();

    const f32x4 Z = {0.f, 0.f, 0.f, 0.f};

    // ---- phase 3: layer 1 (N split: this wave -> cols (wv*2+ntl)*16+n16) ----
    f32x4 Cg[2]    = {Z, Z};
    f32x4 Cf[3][2] = {{Z, Z}, {Z, Z}, {Z, Z}};
#pragma unroll
    for (int ks = 0; ks < 3; ++ks) {                 // K=96 : [mean|var]
        bf16x8 a = *(const bf16x8*)(shB + n16 * 96 + ks * 32 + quad * 8);
#pragma unroll
        for (int ntl = 0; ntl < 2; ++ntl) {
            bf16x8 b = *(const bf16x8*)(WG + ((wv * 2 + ntl) * 16 + n16) * 96 + ks * 32 + quad * 8);
            Cg[ntl] = __builtin_amdgcn_mfma_f32_16x16x32_bf16(a, b, Cg[ntl], 0, 0, 0);
        }
    }
#pragma unroll
    for (int ks = 0; ks < 2; ++ks) {                 // K=64 : view feat
        bf16x8 a0 = *(const bf16x8*)(shC + (0 * 16 + n16) * 72 + ks * 32 + quad * 8);
        bf16x8 a1 = *(const bf16x8*)(shC + (1 * 16 + n16) * 72 + ks * 32 + quad * 8);
        bf16x8 a2 = *(const bf16x8*)(shC + (2 * 16 + n16) * 72 + ks * 32 + quad * 8);
#pragma unroll
        for (int ntl = 0; ntl < 2; ++ntl) {
            bf16x8 b = *(const bf16x8*)(WF + ((wv * 2 + ntl) * 16 + n16) * 72 + ks * 32 + quad * 8);
            Cf[0][ntl] = __builtin_amdgcn_mfma_f32_16x16x32_bf16(a0, b, Cf[0][ntl], 0, 0, 0);
            Cf[1][ntl] = __builtin_amdgcn_mfma_f32_16x16x32_bf16(a1, b, Cf[1][ntl], 0, 0, 0);
            Cf[2][ntl] = __builtin_amdgcn_mfma_f32_16x16x32_bf16(a2, b, Cf[2][ntl], 0, 0, 0);
        }
    }
    // h1 = elu(Cf + Cg + bb1) -> shA [48][72] cols wv*32..wv*32+31
    // (no barrier needed before writes: sfeat readers finished at prior barrier,
    //  shA writes are disjoint from shB/shC MFMA reads)
#pragma unroll
    for (int mt = 0; mt < 3; ++mt)
#pragma unroll
        for (int ntl = 0; ntl < 2; ++ntl) {
            float e0 = eluf(Cf[mt][ntl][0] + Cg[ntl][0] + bb1v[ntl]);
            float e1 = eluf(Cf[mt][ntl][1] + Cg[ntl][1] + bb1v[ntl]);
            float e2 = eluf(Cf[mt][ntl][2] + Cg[ntl][2] + bb1v[ntl]);
            float e3 = eluf(Cf[mt][ntl][3] + Cg[ntl][3] + bb1v[ntl]);
            int col = (wv * 2 + ntl) * 16 + n16;
            int r0  = (mt * 16 + quad * 4) * 72 + col;
            uint u01 = pack2(e0, e1), u23 = pack2(e2, e3);
            shA[r0]           = (ushort)u01;
            shA[r0 + 72]      = (ushort)(u01 >> 16);
            shA[r0 + 144]     = (ushort)u23;
            shA[r0 + 216]     = (ushort)(u23 >> 16);
        }
    __syncthreads();

    // ---- phase 4: layer 2 (N=32, wave owns cols wv*16+n16) ----
    f32x4 C2[3] = {Z, Z, Z};
#pragma unroll
    for (int ks = 0; ks < 2; ++ks) {
        bf16x8 a0 = *(const bf16x8*)(shA + (0 * 16 + n16) * 72 + ks * 32 + quad * 8);
        bf16x8 a1 = *(const bf16x8*)(shA + (1 * 16 + n16) * 72 + ks * 32 + quad * 8);
        bf16x8 a2 = *(const bf16x8*)(shA + (2 * 16 + n16) * 72 + ks * 32 + quad * 8);
        bf16x8 b  = *(const bf16x8*)(W2 + (wv * 16 + n16) * 72 + ks * 32 + quad * 8);
        C2[0] = __builtin_amdgcn_mfma_f32_16x16x32_bf16(a0, b, C2[0], 0, 0, 0);
        C2[1] = __builtin_amdgcn_mfma_f32_16x16x32_bf16(a1, b, C2[1], 0, 0, 0);
        C2[2] = __builtin_amdgcn_mfma_f32_16x16x32_bf16(a2, b, C2[2], 0, 0, 0);
    }
    __syncthreads();                                  // shC (Xf) readers done
    float h2r[3][4];
#pragma unroll
    for (int mt = 0; mt < 3; ++mt) {
        float e0 = eluf(C2[mt][0] + bb2v);
        float e1 = eluf(C2[mt][1] + bb2v);
        float e2 = eluf(C2[mt][2] + bb2v);
        float e3 = eluf(C2[mt][3] + bb2v);
        h2r[mt][0] = e0; h2r[mt][1] = e1; h2r[mt][2] = e2; h2r[mt][3] = e3;
        int r0 = (mt * 16 + quad * 4) * 72 + wv * 16 + n16;
        uint u01 = pack2(e0, e1), u23 = pack2(e2, e3);
        shC[r0]       = (ushort)u01;
        shC[r0 + 72]  = (ushort)(u01 >> 16);
        shC[r0 + 144] = (ushort)u23;
        shC[r0 + 216] = (ushort)(u23 >> 16);
    }
    __syncthreads();

    // ---- phase 5: vis layer 1 (K=32, cols 0..31 of shC only) ----
    f32x4 T1[3] = {Z, Z, Z};
    {
        bf16x8 a0 = *(const bf16x8*)(shC + (0 * 16 + n16) * 72 + quad * 8);
        bf16x8 a1 = *(const bf16x8*)(shC + (1 * 16 + n16) * 72 + quad * 8);
        bf16x8 a2 = *(const bf16x8*)(shC + (2 * 16 + n16) * 72 + quad * 8);
        bf16x8 b  = *(const bf16x8*)(V1 + (wv * 16 + n16) * 40 + quad * 8);
        T1[0] = __builtin_amdgcn_mfma_f32_16x16x32_bf16(a0, b, T1[0], 0, 0, 0);
        T1[1] = __builtin_amdgcn_mfma_f32_16x16x32_bf16(a1, b, T1[1], 0, 0, 0);
        T1[2] = __builtin_amdgcn_mfma_f32_16x16x32_bf16(a2, b, T1[2], 0, 0, 0);
    }
    __syncthreads();                                  // shA (h1) readers done
#pragma unroll
    for (int mt = 0; mt < 3; ++mt) {                  // t1 -> shA cols 0..31
        float e0 = eluf(T1[mt][0] + vb1v);
        float e1 = eluf(T1[mt][1] + vb1v);
        float e2 = eluf(T1[mt][2] + vb1v);
        float e3 = eluf(T1[mt][3] + vb1v);
        int r0 = (mt * 16 + quad * 4) * 72 + wv * 16 + n16;
        uint u01 = pack2(e0, e1), u23 = pack2(e2, e3);
        shA[r0]       = (ushort)u01;
        shA[r0 + 72]  = (ushort)(u01 >> 16);
        shA[r0 + 144] = (ushort)u23;
        shA[r0 + 216] = (ushort)(u23 >> 16);
    }
    __syncthreads();

    // ---- phase 6: vis layer 2 + residual -> x2 (shB [16][104]) ----
    f32x4 T2[3] = {Z, Z, Z};
    {
        bf16x8 a0 = *(const bf16x8*)(shA + (0 * 16 + n16) * 72 + quad * 8);
        bf16x8 a1 = *(const bf16x8*)(shA + (1 * 16 + n16) * 72 + quad * 8);
        bf16x8 a2 = *(const bf16x8*)(shA + (2 * 16 + n16) * 72 + quad * 8);
        bf16x8 b  = *(const bf16x8*)(V2 + (wv * 16 + n16) * 40 + quad * 8);
        T2[0] = __builtin_amdgcn_mfma_f32_16x16x32_bf16(a0, b, T2[0], 0, 0, 0);
        T2[1] = __builtin_amdgcn_mfma_f32_16x16x32_bf16(a1, b, T2[1], 0, 0, 0);
        T2[2] = __builtin_amdgcn_mfma_f32_16x16x32_bf16(a2, b, T2[2], 0, 0, 0);
    }
    __syncthreads();                                  // shB (Xg) readers done
#pragma unroll
    for (int mt = 0; mt < 3; ++mt) {
        float x0 = h2r[mt][0] + eluf(T2[mt][0] + vb2v);
        float x1 = h2r[mt][1] + eluf(T2[mt][1] + vb2v);
        float x2v = h2r[mt][2] + eluf(T2[mt][2] + vb2v);
        float x3 = h2r[mt][3] + eluf(T2[mt][3] + vb2v);
        int col = mt * 32 + wv * 16 + n16;            // v*32 + c concat layout
        int r0  = (quad * 4) * 104 + col;
        uint u01 = pack2(x0, x1), u23 = pack2(x2v, x3);
        shB[r0]       = (ushort)u01;
        shB[r0 + 104] = (ushort)(u01 >> 16);
        shB[r0 + 208] = (ushort)u23;
        shB[r0 + 312] = (ushort)(u23 >> 16);
    }
    __syncthreads();

    // ---- phase 7: r1 = elu(x2 @ R1^T + rb1), N=32 split ----
    f32x4 CR = Z;
#pragma unroll
    for (int ks = 0; ks < 3; ++ks) {                  // K=96
        bf16x8 a = *(const bf16x8*)(shB + n16 * 104 + ks * 32 + quad * 8);
        bf16x8 b = *(const bf16x8*)(R1 + (wv * 16 + n16) * 104 + ks * 32 + quad * 8);
        CR = __builtin_amdgcn_mfma_f32_16x16x32_bf16(a, b, CR, 0, 0, 0);
    }
    __syncthreads();                                  // shC (h2) readers done
    {
        float e0 = eluf(CR[0] + rb1v);
        float e1 = eluf(CR[1] + rb1v);
        float e2 = eluf(CR[2] + rb1v);
        float e3 = eluf(CR[3] + rb1v);
        int r0 = (quad * 4) * 40 + wv * 16 + n16;     // r1 -> shC [16][40]
        uint u01 = pack2(e0, e1), u23 = pack2(e2, e3);
        shC[r0]       = (ushort)u01;
        shC[r0 + 40]  = (ushort)(u01 >> 16);
        shC[r0 + 80]  = (ushort)u23;
        shC[r0 + 120] = (ushort)(u23 >> 16);
    }
    __syncthreads();

    // ---- phase 8: r2 = elu(r1 @ R2^T + rb2) -> fp32 shA [16][20] ----
    f32x4 C3 = Z;
    {
        bf16x8 a = *(const bf16x8*)(shC + n16 * 40 + quad * 8);
        bf16x8 b = *(const bf16x8*)(R2 + n16 * 40 + quad * 8);
        C3 = __builtin_amdgcn_mfma_f32_16x16x32_bf16(a, b, C3, 0, 0, 0);
    }
    __syncthreads();                                  // shA (t1) readers done
    {
        float* r2b = (float*)shA;
#pragma unroll
        for (int rr = 0; rr < 2; ++rr) {              // wave wv writes r = 2wv+rr
            int r = 2 * wv + rr;
            r2b[(quad * 4 + r) * 20 + n16] = eluf(C3[r] + rb2v);
        }
    }
    __syncthreads();

    // ---- phase 9: final 16 -> 3 + sigmoid (fp32), coalesced store ----
    if (tid < 48) {
        const float* r2b = (const float*)shA;
        int p = tid / 3, c = tid - p * 3;
        float s = rb3[c];
        const float* rr = r2b + p * 20;
        const float* w3 = rw3 + c * 16;
#pragma unroll
        for (int k2 = 0; k2 < 16; ++k2) s += rr[k2] * w3[k2];
        out[OUT2_BASE + pbase * 3 + tid] = sigm(s);
    }
}

extern "C" void kernel_launch(void* const* d_in, const int* in_sizes, int n_in,
                              void* d_out, int out_size, void* d_ws, size_t ws_size,
                              hipStream_t stream) {
    const float* feat = (const float*)d_in[0];
    const float* bw1  = (const float*)d_in[1];
    const float* bb1  = (const float*)d_in[2];
    const float* bw2  = (const float*)d_in[3];
    const float* bb2  = (const float*)d_in[4];
    const float* vw1  = (const float*)d_in[5];
    const float* vb1  = (const float*)d_in[6];
    const float* vw2  = (const float*)d_in[7];
    const float* vb2  = (const float*)d_in[8];
    const float* rw1  = (const float*)d_in[9];
    const float* rb1  = (const float*)d_in[10];
    const float* rw2  = (const float*)d_in[11];
    const float* rb2  = (const float*)d_in[12];
    const float* rw3  = (const float*)d_in[13];
    const float* rb3  = (const float*)d_in[14];
    ushort* w  = (ushort*)d_ws;
    float* out = (float*)d_out;

    hipLaunchKernelGGL(prep_k, dim3(77), dim3(256), 0, stream,
                       bw1, bw2, vw1, vw2, rw1, rw2, w);
    hipLaunchKernelGGL(mlp_k, dim3(NPTS / 16), dim3(128), 0, stream,
                       feat, w, bb1, bb2, vb1, vb2, rb1, rb2, rw3, rb3, out);
}